// Round 7
// baseline (614.996 us; speedup 1.0000x reference)
//
#include <hip/hip_runtime.h>
#include <math.h>

typedef __attribute__((ext_vector_type(8))) short short8;   // 8 bf16 (MFMA A/B frag)
typedef __attribute__((ext_vector_type(4))) float f32x4;    // MFMA acc frag
typedef __attribute__((ext_vector_type(2))) float f32x2;
typedef __attribute__((ext_vector_type(4))) unsigned u32x4;

#define PI_OVER_CUTOFF 0.31415926535897932f
#define SLOPE 0.015f

__device__ __forceinline__ unsigned short f2bf(float x) {
    unsigned u = __float_as_uint(x);
    return (unsigned short)((u + 0x7FFFu + ((u >> 16) & 1u)) >> 16);   // RNE
}
// packed f32x2 -> bf16x2, RNE, one instruction. D.lo = cvt(S0), D.hi = cvt(S1).
__device__ __forceinline__ unsigned cvt_pk_bf16(float lo, float hi) {
    unsigned r;
    asm("v_cvt_pk_bf16_f32 %0, %1, %2" : "=v"(r) : "v"(lo), "v"(hi));
    return r;
}
__device__ __forceinline__ short8 pack4(unsigned a, unsigned b, unsigned c, unsigned d) {
    u32x4 t = {a, b, c, d};
    return __builtin_bit_cast(short8, t);
}
// elementwise bf16 product of two bf16x8 frags, computed in f32, repacked bf16
__device__ __forceinline__ short8 mulbf8(short8 w, short8 v) {
    u32x4 uw = __builtin_bit_cast(u32x4, w);
    u32x4 uv = __builtin_bit_cast(u32x4, v);
    unsigned r0, r1, r2, r3;
#define MB(i, r)                                                         \
    {                                                                    \
        float wl = __uint_as_float(uw[i] << 16);                         \
        float wh = __uint_as_float(uw[i] & 0xFFFF0000u);                 \
        float vl = __uint_as_float(uv[i] << 16);                         \
        float vh = __uint_as_float(uv[i] & 0xFFFF0000u);                 \
        r = cvt_pk_bf16(wl * vl, wh * vh);                               \
    }
    MB(0, r0) MB(1, r1) MB(2, r2) MB(3, r3)
#undef MB
    return pack4(r0, r1, r2, r3);
}

// async global(per-lane) -> LDS(wave-uniform base, lane*16B) 16-byte copy
#define GLOAD_LDS16(g, l)                                                                      \
    __builtin_amdgcn_global_load_lds((const __attribute__((address_space(1))) unsigned*)(g),   \
                                     (__attribute__((address_space(3))) unsigned*)(l), 16, 0, 0)

// ---- kernel 0: weights -> bf16, B^T layout, PRE-SWIZZLED, packed contiguous ---
// Output layout in d_ws (u16): [w1s 128x64][w2s 128x128][w3s 128x128][wos 128x128]
// w1s element (c,k<64):  idx c*64  + (k ^ ((c&7)<<3))   (XOR in u16 = 16B granule)
// wXs element (c,k<128): idx c*128 + (k ^ ((c&15)<<3))  (R6-verified, 0 conflicts)
__global__ void prep_weights(const float* __restrict__ w1, const float* __restrict__ w2,
                             const float* __restrict__ w3, const float* __restrict__ wo,
                             unsigned short* __restrict__ wsrc) {
    int i = blockIdx.x * 256 + threadIdx.x;
    unsigned short* w1s = wsrc;
    unsigned short* w2s = wsrc + 128 * 64;
    unsigned short* w3s = w2s + 128 * 128;
    unsigned short* wos = w3s + 128 * 128;
    if (i < 128 * 64) {
        int c = i >> 6, k = i & 63;
        w1s[c * 64 + (k ^ ((c & 7) << 3))] = (k < 50) ? f2bf(w1[c * 50 + k]) : (unsigned short)0;
    }
    if (i < 128 * 128) {
        int c = i >> 7, k = i & 127;
        int d = c * 128 + (k ^ ((c & 15) << 3));
        w2s[d] = f2bf(w2[i]);
        w3s[d] = f2bf(w3[i]);
        wos[d] = f2bf(wo[i] + ((c == k) ? 1.0f : 0.0f));  // fold "+e" residual
    }
}

// ---------------- kernel 1: vp = v @ lin_w.T  -> bf16 [N][128] -----------------
__global__ __launch_bounds__(256) void vp_gemm(const float* __restrict__ v,
                                               const float* __restrict__ lin_w,
                                               unsigned short* __restrict__ vp, int nnodes) {
    const int tid = threadIdx.x;
    const int lane = tid & 63;
    const int wv = tid >> 6;          // wave 0..3 -> col strip of 32
    const int l15 = lane & 15;
    const int l4 = lane >> 4;
    const int r0 = blockIdx.x * 64;
    const int c0 = wv * 32;

    f32x4 acc[4][2] = {};
#pragma unroll
    for (int kf = 0; kf < 4; ++kf) {
        short8 a[4];
#pragma unroll
        for (int mf = 0; mf < 4; ++mf) {
            int row = r0 + mf * 16 + l15;
            f32x4 x0 = {}, x1 = {};
            if (row < nnodes) {
                const float* p = v + (size_t)row * 128 + kf * 32 + l4 * 8;
                x0 = *reinterpret_cast<const f32x4*>(p);
                x1 = *reinterpret_cast<const f32x4*>(p + 4);
            }
            a[mf] = pack4(cvt_pk_bf16(x0[0], x0[1]), cvt_pk_bf16(x0[2], x0[3]),
                          cvt_pk_bf16(x1[0], x1[1]), cvt_pk_bf16(x1[2], x1[3]));
        }
        short8 b[2];
#pragma unroll
        for (int nf = 0; nf < 2; ++nf) {
            const float* p = lin_w + (size_t)(c0 + nf * 16 + l15) * 128 + kf * 32 + l4 * 8;
            f32x4 x0 = *reinterpret_cast<const f32x4*>(p);
            f32x4 x1 = *reinterpret_cast<const f32x4*>(p + 4);
            b[nf] = pack4(cvt_pk_bf16(x0[0], x0[1]), cvt_pk_bf16(x0[2], x0[3]),
                          cvt_pk_bf16(x1[0], x1[1]), cvt_pk_bf16(x1[2], x1[3]));
        }
#pragma unroll
        for (int mf = 0; mf < 4; ++mf)
#pragma unroll
            for (int nf = 0; nf < 2; ++nf)
                acc[mf][nf] = __builtin_amdgcn_mfma_f32_16x16x32_bf16(a[mf], b[nf], acc[mf][nf], 0, 0, 0);
    }
#pragma unroll
    for (int mf = 0; mf < 4; ++mf)
#pragma unroll
        for (int nf = 0; nf < 2; ++nf)
#pragma unroll
            for (int q = 0; q < 4; ++q) {
                int row = r0 + mf * 16 + l4 * 4 + q;
                if (row < nnodes)
                    vp[(size_t)row * 128 + c0 + nf * 16 + l15] = f2bf(acc[mf][nf][q]);
            }
}

// ------------- kernel 2: persistent-weight, barrier-free tile loop ------------
// All 4 weight matrices resident in LDS (112KB, staged ONCE). 4 waves x 32 edges
// per tile, grid-stride over tiles, ZERO barriers in steady state. Cross-tile
// prefetch (2 named register sets) hides all global latency.
__global__ __launch_bounds__(256, 1) void fused_edge(
    const float* __restrict__ dist, const float* __restrict__ dist_emb,
    const int* __restrict__ edge_index,
    const float* __restrict__ b1, const float* __restrict__ b2,
    const float* __restrict__ b3, const float* __restrict__ bo,
    const unsigned short* __restrict__ vp,
    const unsigned short* __restrict__ wsrc,
    float* __restrict__ out, int ntiles) {
    __shared__ __align__(16) unsigned short wall[57344];    // 112KB: w1|w2|w3|wo, swizzled
    __shared__ __align__(16) unsigned char lds_h[4][8192];  // per-wave h, swizzled

    const int tid = threadIdx.x;
    const int lane = tid & 63;
    const int wv = tid >> 6;
    const int l15 = lane & 15;
    const int l4 = lane >> 4;
    unsigned char* hb = lds_h[wv];

    // ---- stage ALL weights once (112 chunks of 1KB, 28 per wave) ----
#pragma unroll
    for (int it = 0; it < 28; ++it) {
        int chunk = it * 4 + wv;
        GLOAD_LDS16(wsrc + chunk * 512 + lane * 8, &wall[chunk * 512]);
    }

    // ---- hoist biases (identity already folded into wo) ----
    float bb1[8], bb2[8], bb3[8], bbo[8];
#pragma unroll
    for (int nf = 0; nf < 8; ++nf) {
        bb1[nf] = b1[nf * 16 + l15];
        bb2[nf] = b2[nf * 16 + l15];
        bb3[nf] = b3[nf * 16 + l15];
        bbo[nf] = bo[nf * 16 + l15];
    }

    f32x4 acc[2][8];

#define W1_READ(nf, kf) \
    (*reinterpret_cast<const short8*>(&wall[((nf) * 16 + l15) * 64 + (((kf) * 32 + l4 * 8) ^ ((l15 & 7) << 3))]))
#define WB_READ(off, nf, kf) \
    (*reinterpret_cast<const short8*>(&wall[(off) + ((nf) * 16 + l15) * 128 + (((kf) * 32 + l4 * 8) ^ (l15 << 3))]))
#define HB_READ(mf, kf) \
    (*reinterpret_cast<const short8*>(hb + ((mf) * 16 + l15) * 256 + (((kf) * 64 + l4 * 16) ^ (l15 << 4))))

#define INIT_ACC(bb)                                                                \
    _Pragma("unroll")                                                               \
    for (int nf = 0; nf < 8; ++nf) {                                                \
        float b = (bb)[nf];                                                         \
        acc[0][nf] = (f32x4){b, b, b, b};                                           \
        acc[1][nf] = acc[0][nf];                                                    \
    }

#define EPILOGUE_TO_LDS()                                                           \
    _Pragma("unroll")                                                               \
    for (int mf = 0; mf < 2; ++mf)                                                  \
        _Pragma("unroll")                                                           \
        for (int nf = 0; nf < 8; ++nf) {                                            \
            f32x4 vv = acc[mf][nf];                                                 \
            _Pragma("unroll")                                                       \
            for (int q = 0; q < 4; ++q) vv[q] = fmaxf(vv[q], SLOPE * vv[q]);        \
            unsigned p01 = cvt_pk_bf16(vv[0], vv[1]);                               \
            unsigned p23 = cvt_pk_bf16(vv[2], vv[3]);                               \
            int col2 = (nf * 16 + l15) * 2;                                         \
            int rb = mf * 16 + l4 * 4;                                              \
            *(unsigned short*)(hb + (rb + 0) * 256 + (col2 ^ ((l4 * 4 + 0) << 4))) = (unsigned short)p01;         \
            *(unsigned short*)(hb + (rb + 1) * 256 + (col2 ^ ((l4 * 4 + 1) << 4))) = (unsigned short)(p01 >> 16); \
            *(unsigned short*)(hb + (rb + 2) * 256 + (col2 ^ ((l4 * 4 + 2) << 4))) = (unsigned short)p23;         \
            *(unsigned short*)(hb + (rb + 3) * 256 + (col2 ^ ((l4 * 4 + 3) << 4))) = (unsigned short)(p23 >> 16); \
        }

    // ---- two named prefetch sets (rule #20: no runtime indexing) ----
    long eoA, eoB;
    int jmA[2], jmB[2];
    float ddA[2][4], ddB[2][4];
    f32x2 embA[2][2][4], embB[2][2][4];

#define PREFETCH(S, tt)                                                             \
    {                                                                               \
        eo##S = (long)(tt) * 128 + wv * 32;                                         \
        _Pragma("unroll")                                                           \
        for (int mf = 0; mf < 2; ++mf) {                                            \
            jm##S[mf] = edge_index[eo##S + mf * 16 + l15] * 128;                    \
            _Pragma("unroll")                                                       \
            for (int q = 0; q < 4; ++q)                                             \
                dd##S[mf][q] = dist[eo##S + mf * 16 + l4 * 4 + q];                  \
            _Pragma("unroll")                                                       \
            for (int kf = 0; kf < 2; ++kf) {                                        \
                const float* src = dist_emb + (eo##S + mf * 16 + l15) * 50 + kf * 32 + l4 * 8; \
                _Pragma("unroll")                                                   \
                for (int p = 0; p < 4; ++p) {                                       \
                    int k2 = kf * 32 + l4 * 8 + 2 * p;                              \
                    emb##S[mf][kf][p] = (k2 < 50)                                   \
                        ? *reinterpret_cast<const f32x2*>(src + 2 * p)              \
                        : (f32x2){0.f, 0.f};                                        \
                }                                                                   \
            }                                                                       \
        }                                                                           \
    }

#define BODY(C, N, tn)                                                              \
    {                                                                               \
        /* vp gather for CURRENT tile: consumed in stage 4, ~3k cyc cover */        \
        short8 vpr[2][4];                                                           \
        _Pragma("unroll")                                                           \
        for (int mf = 0; mf < 2; ++mf)                                              \
            _Pragma("unroll")                                                       \
            for (int kf = 0; kf < 4; ++kf)                                          \
                vpr[mf][kf] = *reinterpret_cast<const short8*>(vp + jm##C[mf] + kf * 32 + l4 * 8); \
        /* prefetch NEXT tile's inputs: consumed next BODY, full-tile cover */      \
        if ((tn) < ntiles) PREFETCH(N, tn)                                          \
        /* stage 1: h1 = leaky(emb @ w1.T + b1) */                                  \
        INIT_ACC(bb1)                                                               \
        _Pragma("unroll")                                                           \
        for (int kf = 0; kf < 2; ++kf) {                                            \
            short8 a0 = pack4(cvt_pk_bf16(emb##C[0][kf][0][0], emb##C[0][kf][0][1]),\
                              cvt_pk_bf16(emb##C[0][kf][1][0], emb##C[0][kf][1][1]),\
                              cvt_pk_bf16(emb##C[0][kf][2][0], emb##C[0][kf][2][1]),\
                              cvt_pk_bf16(emb##C[0][kf][3][0], emb##C[0][kf][3][1]));\
            short8 a1 = pack4(cvt_pk_bf16(emb##C[1][kf][0][0], emb##C[1][kf][0][1]),\
                              cvt_pk_bf16(emb##C[1][kf][1][0], emb##C[1][kf][1][1]),\
                              cvt_pk_bf16(emb##C[1][kf][2][0], emb##C[1][kf][2][1]),\
                              cvt_pk_bf16(emb##C[1][kf][3][0], emb##C[1][kf][3][1]));\
            _Pragma("unroll")                                                       \
            for (int nf = 0; nf < 8; ++nf) {                                        \
                short8 b = W1_READ(nf, kf);                                         \
                acc[0][nf] = __builtin_amdgcn_mfma_f32_16x16x32_bf16(a0, b, acc[0][nf], 0, 0, 0); \
                acc[1][nf] = __builtin_amdgcn_mfma_f32_16x16x32_bf16(a1, b, acc[1][nf], 0, 0, 0); \
            }                                                                       \
        }                                                                           \
        EPILOGUE_TO_LDS()                                                           \
        /* stage 2: h2 = leaky(h1 @ w2.T + b2) */                                   \
        INIT_ACC(bb2)                                                               \
        _Pragma("unroll")                                                           \
        for (int kf = 0; kf < 4; ++kf) {                                            \
            short8 a0 = HB_READ(0, kf);                                             \
            short8 a1 = HB_READ(1, kf);                                             \
            _Pragma("unroll")                                                       \
            for (int nf = 0; nf < 8; ++nf) {                                        \
                short8 b = WB_READ(8192, nf, kf);                                   \
                acc[0][nf] = __builtin_amdgcn_mfma_f32_16x16x32_bf16(a0, b, acc[0][nf], 0, 0, 0); \
                acc[1][nf] = __builtin_amdgcn_mfma_f32_16x16x32_bf16(a1, b, acc[1][nf], 0, 0, 0); \
            }                                                                       \
        }                                                                           \
        EPILOGUE_TO_LDS()                                                           \
        /* stage 3: W = (h2 @ w3.T + b3) * C(dist) */                               \
        INIT_ACC(bb3)                                                               \
        _Pragma("unroll")                                                           \
        for (int kf = 0; kf < 4; ++kf) {                                            \
            short8 a0 = HB_READ(0, kf);                                             \
            short8 a1 = HB_READ(1, kf);                                             \
            _Pragma("unroll")                                                       \
            for (int nf = 0; nf < 8; ++nf) {                                        \
                short8 b = WB_READ(24576, nf, kf);                                  \
                acc[0][nf] = __builtin_amdgcn_mfma_f32_16x16x32_bf16(a0, b, acc[0][nf], 0, 0, 0); \
                acc[1][nf] = __builtin_amdgcn_mfma_f32_16x16x32_bf16(a1, b, acc[1][nf], 0, 0, 0); \
            }                                                                       \
        }                                                                           \
        {                                                                           \
            float Cw[2][4];                                                         \
            _Pragma("unroll")                                                       \
            for (int mf = 0; mf < 2; ++mf)                                          \
                _Pragma("unroll")                                                   \
                for (int q = 0; q < 4; ++q)                                         \
                    Cw[mf][q] = 0.5f * (__cosf(dd##C[mf][q] * PI_OVER_CUTOFF) + 1.0f); \
            _Pragma("unroll")                                                       \
            for (int mf = 0; mf < 2; ++mf)                                          \
                _Pragma("unroll")                                                   \
                for (int nf = 0; nf < 8; ++nf) {                                    \
                    f32x4 vv = acc[mf][nf];                                         \
                    _Pragma("unroll")                                               \
                    for (int q = 0; q < 4; ++q) vv[q] = vv[q] * Cw[mf][q];          \
                    unsigned p01 = cvt_pk_bf16(vv[0], vv[1]);                       \
                    unsigned p23 = cvt_pk_bf16(vv[2], vv[3]);                       \
                    int col2 = (nf * 16 + l15) * 2;                                 \
                    int rb = mf * 16 + l4 * 4;                                      \
                    *(unsigned short*)(hb + (rb + 0) * 256 + (col2 ^ ((l4 * 4 + 0) << 4))) = (unsigned short)p01;         \
                    *(unsigned short*)(hb + (rb + 1) * 256 + (col2 ^ ((l4 * 4 + 1) << 4))) = (unsigned short)(p01 >> 16); \
                    *(unsigned short*)(hb + (rb + 2) * 256 + (col2 ^ ((l4 * 4 + 2) << 4))) = (unsigned short)p23;         \
                    *(unsigned short*)(hb + (rb + 3) * 256 + (col2 ^ ((l4 * 4 + 3) << 4))) = (unsigned short)(p23 >> 16); \
                }                                                                   \
        }                                                                           \
        /* stage 4: out = (vp[j] .* W) @ (wo + I).T + bo */                         \
        INIT_ACC(bbo)                                                               \
        _Pragma("unroll")                                                           \
        for (int kf = 0; kf < 4; ++kf) {                                            \
            short8 a0 = mulbf8(HB_READ(0, kf), vpr[0][kf]);                         \
            short8 a1 = mulbf8(HB_READ(1, kf), vpr[1][kf]);                         \
            _Pragma("unroll")                                                       \
            for (int nf = 0; nf < 8; ++nf) {                                        \
                short8 b = WB_READ(40960, nf, kf);                                  \
                acc[0][nf] = __builtin_amdgcn_mfma_f32_16x16x32_bf16(a0, b, acc[0][nf], 0, 0, 0); \
                acc[1][nf] = __builtin_amdgcn_mfma_f32_16x16x32_bf16(a1, b, acc[1][nf], 0, 0, 0); \
            }                                                                       \
        }                                                                           \
        {                                                                           \
            float* op = out + eo##C * 128;                                          \
            _Pragma("unroll")                                                       \
            for (int mf = 0; mf < 2; ++mf)                                          \
                _Pragma("unroll")                                                   \
                for (int nf = 0; nf < 8; ++nf)                                      \
                    _Pragma("unroll")                                               \
                    for (int q = 0; q < 4; ++q)                                     \
                        op[(size_t)(mf * 16 + l4 * 4 + q) * 128 + nf * 16 + l15] = acc[mf][nf][q]; \
        }                                                                           \
    }

    // ---- prologue prefetch for first tile, then weights-ready barrier ----
    int t = blockIdx.x;
    const int stride = gridDim.x;
    PREFETCH(A, t)
    __syncthreads();   // the ONLY barrier: weights staged

    for (;;) {
        int tn = t + stride;
        BODY(A, B, tn)
        t = tn;
        if (t >= ntiles) break;
        tn = t + stride;
        BODY(B, A, tn)
        t = tn;
        if (t >= ntiles) break;
    }
#undef BODY
#undef PREFETCH
#undef EPILOGUE_TO_LDS
#undef INIT_ACC
#undef HB_READ
#undef WB_READ
#undef W1_READ
}

extern "C" void kernel_launch(void* const* d_in, const int* in_sizes, int n_in,
                              void* d_out, int out_size, void* d_ws, size_t ws_size,
                              hipStream_t stream) {
    const float* v        = (const float*)d_in[0];
    const float* dist     = (const float*)d_in[1];
    const float* dist_emb = (const float*)d_in[2];
    const int*   edge_idx = (const int*)d_in[3];
    const float* lin_w    = (const float*)d_in[4];
    const float* w1 = (const float*)d_in[5];
    const float* b1 = (const float*)d_in[6];
    const float* w2 = (const float*)d_in[7];
    const float* b2 = (const float*)d_in[8];
    const float* w3 = (const float*)d_in[9];
    const float* b3 = (const float*)d_in[10];
    const float* wo = (const float*)d_in[11];
    const float* bo = (const float*)d_in[12];
    float* out = (float*)d_out;

    const int nnodes = in_sizes[0] / 128;   // 50000
    const int E = in_sizes[1];              // 1600000 (multiple of 128)
    const int ntiles = E / 128;

    unsigned short* vp   = (unsigned short*)d_ws;           // [nnodes][128] bf16
    unsigned short* wsrc = vp + (size_t)nnodes * 128;       // 57344 u16, packed+swizzled

    prep_weights<<<64, 256, 0, stream>>>(w1, w2, w3, wo, wsrc);
    vp_gemm<<<(nnodes + 63) / 64, 256, 0, stream>>>(v, lin_w, vp, nnodes);
    fused_edge<<<768, 256, 0, stream>>>(dist, dist_emb, edge_idx,
                                        b1, b2, b3, bo, vp, wsrc, out, ntiles);
}

// Round 8
// 593.489 us; speedup vs baseline: 1.0362x; 1.0362x over previous
//
#include <hip/hip_runtime.h>
#include <math.h>

typedef __attribute__((ext_vector_type(8))) short short8;   // 8 bf16 (MFMA A/B frag)
typedef __attribute__((ext_vector_type(4))) float f32x4;    // MFMA acc frag
typedef __attribute__((ext_vector_type(2))) float f32x2;
typedef __attribute__((ext_vector_type(4))) unsigned u32x4;
typedef __attribute__((ext_vector_type(2))) unsigned u32x2;

#define PI_OVER_CUTOFF 0.31415926535897932f
#define SLOPE 0.015f

__device__ __forceinline__ unsigned short f2bf(float x) {
    unsigned u = __float_as_uint(x);
    return (unsigned short)((u + 0x7FFFu + ((u >> 16) & 1u)) >> 16);   // RNE
}
// packed f32x2 -> bf16x2, RNE, one instruction. D.lo = cvt(S0), D.hi = cvt(S1).
__device__ __forceinline__ unsigned cvt_pk_bf16(float lo, float hi) {
    unsigned r;
    asm("v_cvt_pk_bf16_f32 %0, %1, %2" : "=v"(r) : "v"(lo), "v"(hi));
    return r;
}
__device__ __forceinline__ short8 pack4(unsigned a, unsigned b, unsigned c, unsigned d) {
    u32x4 t = {a, b, c, d};
    return __builtin_bit_cast(short8, t);
}
// elementwise bf16 product of two bf16x8 frags, computed in f32, repacked bf16
__device__ __forceinline__ short8 mulbf8(short8 w, short8 v) {
    u32x4 uw = __builtin_bit_cast(u32x4, w);
    u32x4 uv = __builtin_bit_cast(u32x4, v);
    unsigned r0, r1, r2, r3;
#define MB(i, r)                                                         \
    {                                                                    \
        float wl = __uint_as_float(uw[i] << 16);                         \
        float wh = __uint_as_float(uw[i] & 0xFFFF0000u);                 \
        float vl = __uint_as_float(uv[i] << 16);                         \
        float vh = __uint_as_float(uv[i] & 0xFFFF0000u);                 \
        r = cvt_pk_bf16(wl * vl, wh * vh);                               \
    }
    MB(0, r0) MB(1, r1) MB(2, r2) MB(3, r3)
#undef MB
    return pack4(r0, r1, r2, r3);
}

// async global(per-lane) -> LDS(wave-uniform base, lane*16B) 16-byte copy
#define GLOAD_LDS16(g, l)                                                                      \
    __builtin_amdgcn_global_load_lds((const __attribute__((address_space(1))) unsigned*)(g),   \
                                     (__attribute__((address_space(3))) unsigned*)(l), 16, 0, 0)

// ---- kernel 0: weights -> bf16 ------------------------------------------------
// w1p: [128][64] row-major, NOT swizzled (read from global as A-frags, L1-hot).
// wsrc: w2|w3|wo each [128][128], PRE-SWIZZLED: (c,k) at c*128 + (k ^ ((c&15)<<3))
//       so linear global_load_lds + swizzled ds_read is conflict-free (R6/R7 family).
__global__ void prep_weights(const float* __restrict__ w1, const float* __restrict__ w2,
                             const float* __restrict__ w3, const float* __restrict__ wo,
                             unsigned short* __restrict__ w1p, unsigned short* __restrict__ wsrc) {
    int i = blockIdx.x * 256 + threadIdx.x;
    unsigned short* w2s = wsrc;
    unsigned short* w3s = wsrc + 128 * 128;
    unsigned short* wos = w3s + 128 * 128;
    if (i < 128 * 64) {
        int c = i >> 6, k = i & 63;
        w1p[i] = (k < 50) ? f2bf(w1[c * 50 + k]) : (unsigned short)0;  // pad K 50->64
    }
    if (i < 128 * 128) {
        int c = i >> 7, k = i & 127;
        int d = c * 128 + (k ^ ((c & 15) << 3));
        w2s[d] = f2bf(w2[i]);
        w3s[d] = f2bf(w3[i]);
        wos[d] = f2bf(wo[i] + ((c == k) ? 1.0f : 0.0f));  // fold "+e" residual
    }
}

// ---------------- kernel 1: vp = v @ lin_w.T  -> bf16 [N][128] -----------------
__global__ __launch_bounds__(256) void vp_gemm(const float* __restrict__ v,
                                               const float* __restrict__ lin_w,
                                               unsigned short* __restrict__ vp, int nnodes) {
    const int tid = threadIdx.x;
    const int lane = tid & 63;
    const int wv = tid >> 6;          // wave 0..3 -> col strip of 32
    const int l15 = lane & 15;
    const int l4 = lane >> 4;
    const int r0 = blockIdx.x * 64;
    const int c0 = wv * 32;

    f32x4 acc[4][2] = {};
#pragma unroll
    for (int kf = 0; kf < 4; ++kf) {
        short8 a[4];
#pragma unroll
        for (int mf = 0; mf < 4; ++mf) {
            int row = r0 + mf * 16 + l15;
            f32x4 x0 = {}, x1 = {};
            if (row < nnodes) {
                const float* p = v + (size_t)row * 128 + kf * 32 + l4 * 8;
                x0 = *reinterpret_cast<const f32x4*>(p);
                x1 = *reinterpret_cast<const f32x4*>(p + 4);
            }
            a[mf] = pack4(cvt_pk_bf16(x0[0], x0[1]), cvt_pk_bf16(x0[2], x0[3]),
                          cvt_pk_bf16(x1[0], x1[1]), cvt_pk_bf16(x1[2], x1[3]));
        }
        short8 b[2];
#pragma unroll
        for (int nf = 0; nf < 2; ++nf) {
            const float* p = lin_w + (size_t)(c0 + nf * 16 + l15) * 128 + kf * 32 + l4 * 8;
            f32x4 x0 = *reinterpret_cast<const f32x4*>(p);
            f32x4 x1 = *reinterpret_cast<const f32x4*>(p + 4);
            b[nf] = pack4(cvt_pk_bf16(x0[0], x0[1]), cvt_pk_bf16(x0[2], x0[3]),
                          cvt_pk_bf16(x1[0], x1[1]), cvt_pk_bf16(x1[2], x1[3]));
        }
#pragma unroll
        for (int mf = 0; mf < 4; ++mf)
#pragma unroll
            for (int nf = 0; nf < 2; ++nf)
                acc[mf][nf] = __builtin_amdgcn_mfma_f32_16x16x32_bf16(a[mf], b[nf], acc[mf][nf], 0, 0, 0);
    }
#pragma unroll
    for (int mf = 0; mf < 4; ++mf)
#pragma unroll
        for (int nf = 0; nf < 2; ++nf)
#pragma unroll
            for (int q = 0; q < 4; ++q) {
                int row = r0 + mf * 16 + l4 * 4 + q;
                if (row < nnodes)
                    vp[(size_t)row * 128 + c0 + nf * 16 + l15] = f2bf(acc[mf][nf][q]);
            }
}

// ------ kernel 2: 8-wave persistent, barrier-free, swapped-operand MFMA -------
// D[outch][edge]: edge = lane&15 -> h writeback is ds_write_b64, Cw/bias vectorize.
// w2/w3/wo resident in LDS (96KB, staged once); h private 8KB/wave (64KB). 160KB.
// 2 waves/SIMD: dependent-chain latency of one wave hides under the other.
__global__ __launch_bounds__(512, 2) void fused_edge(
    const float* __restrict__ dist, const float* __restrict__ dist_emb,
    const int* __restrict__ edge_index,
    const float* __restrict__ b1, const float* __restrict__ b2,
    const float* __restrict__ b3, const float* __restrict__ bo,
    const unsigned short* __restrict__ vp,
    const unsigned short* __restrict__ w1p, const unsigned short* __restrict__ wsrc,
    float* __restrict__ out, int ntiles) {
    __shared__ __align__(16) unsigned short wlds[3 * 16384];  // 96KB: w2|w3|wo swizzled
    __shared__ __align__(16) unsigned char lds_h[8][8192];    // per-wave [32][256B] swizzled

    const int tid = threadIdx.x;
    const int lane = tid & 63;
    const int wv = tid >> 6;          // 0..7
    const int l15 = lane & 15;
    const int l4 = lane >> 4;
    unsigned char* hb = lds_h[wv];

    // ---- stage w2|w3|wo once: 96 KB = 96 chunks of 1KB, 12 per wave ----
#pragma unroll
    for (int it = 0; it < 12; ++it) {
        int chunk = it * 8 + wv;
        GLOAD_LDS16(wsrc + chunk * 512 + lane * 8, &wlds[chunk * 512]);
    }

    // ---- biases as f32x4 (outch = nf*16 + l4*4 + q) ----
    f32x4 bb1[8], bb2[8], bb3[8], bbo[8];
#pragma unroll
    for (int nf = 0; nf < 8; ++nf) {
        bb1[nf] = *reinterpret_cast<const f32x4*>(b1 + nf * 16 + l4 * 4);
        bb2[nf] = *reinterpret_cast<const f32x4*>(b2 + nf * 16 + l4 * 4);
        bb3[nf] = *reinterpret_cast<const f32x4*>(b3 + nf * 16 + l4 * 4);
        bbo[nf] = *reinterpret_cast<const f32x4*>(bo + nf * 16 + l4 * 4);
    }

#define WL_READ(widx, nf, kf) \
    (*reinterpret_cast<const short8*>(&wlds[(widx) * 16384 + ((nf) * 16 + l15) * 128 + (((kf) * 32 + l4 * 8) ^ (l15 << 3))]))
#define HB_READ(e2, kf) \
    (*reinterpret_cast<const short8*>(hb + ((e2) * 16 + l15) * 256 + (((kf) * 64 + l4 * 16) ^ (l15 << 4))))
// h[edge=e2*16+l15][outch nf*16+l4*4 .. +3] as one b64 (4 consecutive bf16)
#define H_WRITE(e2, nf, pw) \
    (*reinterpret_cast<u32x2*>(hb + ((e2) * 16 + l15) * 256 + ((((nf) * 32 + l4 * 8)) ^ (l15 << 4))) = (pw))

#define EPI_LEAKY()                                                                 \
    _Pragma("unroll")                                                               \
    for (int e2 = 0; e2 < 2; ++e2)                                                  \
        _Pragma("unroll")                                                           \
        for (int nf = 0; nf < 8; ++nf) {                                            \
            f32x4 vv = acc[e2][nf];                                                 \
            _Pragma("unroll")                                                       \
            for (int q = 0; q < 4; ++q) vv[q] = fmaxf(vv[q], SLOPE * vv[q]);        \
            u32x2 pw = {cvt_pk_bf16(vv[0], vv[1]), cvt_pk_bf16(vv[2], vv[3])};      \
            H_WRITE(e2, nf, pw);                                                    \
        }

    // ---- two named prefetch sets (edge-side inputs; edge = e2*16 + l15) ----
    long eoA, eoB;
    int jmA[2], jmB[2];
    float ddA[2], ddB[2];
    f32x2 embA[2][2][4], embB[2][2][4];

#define PREFETCH(S, tt)                                                             \
    {                                                                               \
        eo##S = (long)(tt) * 256 + wv * 32;                                         \
        _Pragma("unroll")                                                           \
        for (int e2 = 0; e2 < 2; ++e2) {                                            \
            jm##S[e2] = edge_index[eo##S + e2 * 16 + l15] * 128;                    \
            dd##S[e2] = dist[eo##S + e2 * 16 + l15];                                \
            _Pragma("unroll")                                                       \
            for (int kf = 0; kf < 2; ++kf) {                                        \
                const float* src = dist_emb + (eo##S + e2 * 16 + l15) * 50 + kf * 32 + l4 * 8; \
                _Pragma("unroll")                                                   \
                for (int p = 0; p < 4; ++p) {                                       \
                    int k2 = kf * 32 + l4 * 8 + 2 * p;                              \
                    emb##S[e2][kf][p] = (k2 < 50)                                   \
                        ? *reinterpret_cast<const f32x2*>(src + 2 * p)              \
                        : (f32x2){0.f, 0.f};                                        \
                }                                                                   \
            }                                                                       \
        }                                                                           \
    }

    int t = blockIdx.x;
    const int stride = gridDim.x;
    PREFETCH(A, t)
    __syncthreads();   // the ONLY barrier: weights staged (implicit vmcnt drain)

    f32x4 acc[2][8];
    for (;;) {
        // w1 A-frags (16KB table, L1-hot) + vp gather: issue before compute
        short8 w1f[2][8];
#pragma unroll
        for (int kf = 0; kf < 2; ++kf)
#pragma unroll
            for (int nf = 0; nf < 8; ++nf)
                w1f[kf][nf] = *reinterpret_cast<const short8*>(w1p + (nf * 16 + l15) * 64 + kf * 32 + l4 * 8);
        short8 vpr[2][4];
#pragma unroll
        for (int e2 = 0; e2 < 2; ++e2)
#pragma unroll
            for (int kf = 0; kf < 4; ++kf)
                vpr[e2][kf] = *reinterpret_cast<const short8*>(vp + jmA[e2] + kf * 32 + l4 * 8);

        int tn = t + stride;
        int tc = (tn < ntiles) ? tn : (ntiles - 1);
        PREFETCH(B, tc)   // next tile's edge inputs; consumed next iteration

        // ===== stage 1: h1 = leaky(w1 @ emb^T + b1)  [D: outch x edge] =====
#pragma unroll
        for (int nf = 0; nf < 8; ++nf) { acc[0][nf] = bb1[nf]; acc[1][nf] = bb1[nf]; }
#pragma unroll
        for (int kf = 0; kf < 2; ++kf) {
            short8 h0 = pack4(cvt_pk_bf16(embA[0][kf][0][0], embA[0][kf][0][1]),
                              cvt_pk_bf16(embA[0][kf][1][0], embA[0][kf][1][1]),
                              cvt_pk_bf16(embA[0][kf][2][0], embA[0][kf][2][1]),
                              cvt_pk_bf16(embA[0][kf][3][0], embA[0][kf][3][1]));
            short8 h1 = pack4(cvt_pk_bf16(embA[1][kf][0][0], embA[1][kf][0][1]),
                              cvt_pk_bf16(embA[1][kf][1][0], embA[1][kf][1][1]),
                              cvt_pk_bf16(embA[1][kf][2][0], embA[1][kf][2][1]),
                              cvt_pk_bf16(embA[1][kf][3][0], embA[1][kf][3][1]));
#pragma unroll
            for (int nf = 0; nf < 8; ++nf) {
                acc[0][nf] = __builtin_amdgcn_mfma_f32_16x16x32_bf16(w1f[kf][nf], h0, acc[0][nf], 0, 0, 0);
                acc[1][nf] = __builtin_amdgcn_mfma_f32_16x16x32_bf16(w1f[kf][nf], h1, acc[1][nf], 0, 0, 0);
            }
        }
        EPI_LEAKY()

        // ===== stage 2: h2 = leaky(w2 @ h1 + b2) =====
#pragma unroll
        for (int nf = 0; nf < 8; ++nf) { acc[0][nf] = bb2[nf]; acc[1][nf] = bb2[nf]; }
#pragma unroll
        for (int kf = 0; kf < 4; ++kf) {
            short8 h0 = HB_READ(0, kf);
            short8 h1 = HB_READ(1, kf);
#pragma unroll
            for (int nf = 0; nf < 8; ++nf) {
                short8 a = WL_READ(0, nf, kf);
                acc[0][nf] = __builtin_amdgcn_mfma_f32_16x16x32_bf16(a, h0, acc[0][nf], 0, 0, 0);
                acc[1][nf] = __builtin_amdgcn_mfma_f32_16x16x32_bf16(a, h1, acc[1][nf], 0, 0, 0);
            }
        }
        EPI_LEAKY()

        // ===== stage 3: W = (w3 @ h2 + b3) * C(dist)  [C scalar per lane!] =====
#pragma unroll
        for (int nf = 0; nf < 8; ++nf) { acc[0][nf] = bb3[nf]; acc[1][nf] = bb3[nf]; }
#pragma unroll
        for (int kf = 0; kf < 4; ++kf) {
            short8 h0 = HB_READ(0, kf);
            short8 h1 = HB_READ(1, kf);
#pragma unroll
            for (int nf = 0; nf < 8; ++nf) {
                short8 a = WL_READ(1, nf, kf);
                acc[0][nf] = __builtin_amdgcn_mfma_f32_16x16x32_bf16(a, h0, acc[0][nf], 0, 0, 0);
                acc[1][nf] = __builtin_amdgcn_mfma_f32_16x16x32_bf16(a, h1, acc[1][nf], 0, 0, 0);
            }
        }
        {
            float Cw0 = 0.5f * (__cosf(ddA[0] * PI_OVER_CUTOFF) + 1.0f);
            float Cw1 = 0.5f * (__cosf(ddA[1] * PI_OVER_CUTOFF) + 1.0f);
#pragma unroll
            for (int e2 = 0; e2 < 2; ++e2) {
                float Cw = e2 ? Cw1 : Cw0;
#pragma unroll
                for (int nf = 0; nf < 8; ++nf) {
                    f32x4 vv = acc[e2][nf];
#pragma unroll
                    for (int q = 0; q < 4; ++q) vv[q] *= Cw;
                    u32x2 pw = {cvt_pk_bf16(vv[0], vv[1]), cvt_pk_bf16(vv[2], vv[3])};
                    H_WRITE(e2, nf, pw);
                }
            }
        }

        // ===== stage 4: out = wo+I @ (vp[j] .* W) + bo =====
#pragma unroll
        for (int nf = 0; nf < 8; ++nf) { acc[0][nf] = bbo[nf]; acc[1][nf] = bbo[nf]; }
#pragma unroll
        for (int kf = 0; kf < 4; ++kf) {
            short8 h0 = mulbf8(HB_READ(0, kf), vpr[0][kf]);
            short8 h1 = mulbf8(HB_READ(1, kf), vpr[1][kf]);
#pragma unroll
            for (int nf = 0; nf < 8; ++nf) {
                short8 a = WL_READ(2, nf, kf);
                acc[0][nf] = __builtin_amdgcn_mfma_f32_16x16x32_bf16(a, h0, acc[0][nf], 0, 0, 0);
                acc[1][nf] = __builtin_amdgcn_mfma_f32_16x16x32_bf16(a, h1, acc[1][nf], 0, 0, 0);
            }
        }
#pragma unroll
        for (int e2 = 0; e2 < 2; ++e2) {
            float* op = out + (size_t)(eoA + e2 * 16 + l15) * 128 + l4 * 4;
#pragma unroll
            for (int nf = 0; nf < 8; ++nf)
                *reinterpret_cast<f32x4*>(op + nf * 16) = acc[e2][nf];
        }

        // rotate prefetch sets
        t = tn;
        if (t >= ntiles) break;
        eoA = eoB;
#pragma unroll
        for (int e2 = 0; e2 < 2; ++e2) {
            jmA[e2] = jmB[e2];
            ddA[e2] = ddB[e2];
#pragma unroll
            for (int kf = 0; kf < 2; ++kf)
#pragma unroll
                for (int p = 0; p < 4; ++p)
                    embA[e2][kf][p] = embB[e2][kf][p];
        }
    }
#undef PREFETCH
#undef EPI_LEAKY
#undef H_WRITE
#undef HB_READ
#undef WL_READ
}

extern "C" void kernel_launch(void* const* d_in, const int* in_sizes, int n_in,
                              void* d_out, int out_size, void* d_ws, size_t ws_size,
                              hipStream_t stream) {
    const float* v        = (const float*)d_in[0];
    const float* dist     = (const float*)d_in[1];
    const float* dist_emb = (const float*)d_in[2];
    const int*   edge_idx = (const int*)d_in[3];
    const float* lin_w    = (const float*)d_in[4];
    const float* w1 = (const float*)d_in[5];
    const float* b1 = (const float*)d_in[6];
    const float* w2 = (const float*)d_in[7];
    const float* b2 = (const float*)d_in[8];
    const float* w3 = (const float*)d_in[9];
    const float* b3 = (const float*)d_in[10];
    const float* wo = (const float*)d_in[11];
    const float* bo = (const float*)d_in[12];
    float* out = (float*)d_out;

    const int nnodes = in_sizes[0] / 128;   // 50000
    const int E = in_sizes[1];              // 1600000 (multiple of 256)
    const int ntiles = E / 256;

    unsigned short* vp   = (unsigned short*)d_ws;           // [nnodes][128] bf16
    unsigned short* w1p  = vp + (size_t)nnodes * 128;       // [128][64] row-major
    unsigned short* wsrc = w1p + 128 * 64;                  // 3x[128][128] swizzled

    prep_weights<<<64, 256, 0, stream>>>(w1, w2, w3, wo, w1p, wsrc);
    vp_gemm<<<(nnodes + 63) / 64, 256, 0, stream>>>(v, lin_w, vp, nnodes);
    fused_edge<<<256, 512, 0, stream>>>(dist, dist_emb, edge_idx,
                                        b1, b2, b3, bo, vp, w1p, wsrc, out, ntiles);
}